// Round 8
// baseline (179.679 us; speedup 1.0000x reference)
//
#include <hip/hip_runtime.h>
#include <math.h>
#include <limits.h>

#define NB 16
#define NC 21
#define NANCH 65536
#define NM 20

#define POS_THR 0.5f
#define NEG_THR 0.4f
#define F_ALPHA 0.25f
#define MIN_POS_TOPK 10
#define NEG_POS_RATIO 3

#define NBINS 256            // value bins: (unsigned)(score * 256.0f), exact & monotone
#define EQCAP 2048
#define APT 4                // anchors per thread in k_iou
#define IOU_TPB 1024         // threads per k_iou block
#define IOU_BPI 16           // k_iou blocks per image (65536 / (1024*4))
#define NCAND (256 * MIN_POS_TOPK)

// value-based score bin: monotone in float bits for non-negative scores.
// s * 2^8 is exact (exponent shift); unsigned truncation is monotone.
__device__ __forceinline__ unsigned score_bin(float s) {
  unsigned b = (unsigned)(s * 256.0f);
  return b > (NBINS - 1) ? (NBINS - 1) : b;
}

// wave(64)-wide argmax of (v desc, i asc)
__device__ __forceinline__ void argmax64(float& v, int& i) {
  #pragma unroll
  for (int m = 32; m >= 1; m >>= 1) {
    float ov = __shfl_xor(v, m, 64);
    int   oi = __shfl_xor(i, m, 64);
    if (ov > v || (ov == v && oi < i)) { v = ov; i = oi; }
  }
}

// ---------- K0: zero hist + scalar accumulators ----------
__global__ void k_init(unsigned* hist, int* pos_cnt, int* neg_cnt,
                       int* eqcnt, float* sums) {
  size_t tid = (size_t)blockIdx.x * blockDim.x + threadIdx.x;
  size_t tot = (size_t)NB * NBINS;
  for (size_t j = tid; j < tot; j += (size_t)gridDim.x * blockDim.x) hist[j] = 0u;
  if (blockIdx.x == 0) {
    int t = threadIdx.x;
    if (t < NB) { pos_cnt[t] = 0; neg_cnt[t] = 0; eqcnt[t] = 0; }
    if (t < 3 * NB) sums[t] = 0.0f;
  }
}

// ---------- K1: decode + IoU max/argmax + counts + LDS score hist + wave top-10 ----------
__global__ __launch_bounds__(IOU_TPB)
void k_iou(const float* __restrict__ reg, const float* __restrict__ anchors,
           const float* __restrict__ tb, const float* __restrict__ scores,
           float* __restrict__ miou, int* __restrict__ midx,
           int* __restrict__ pos_cnt, int* __restrict__ neg_cnt,
           unsigned* __restrict__ hist,
           float* __restrict__ cand_val, int* __restrict__ cand_idx) {
  __shared__ float4 tbs4[NM];
  __shared__ float  tarea[NM];
  __shared__ unsigned lhist[NBINS];
  int b   = blockIdx.x >> 4;            // 16 blocks per image
  int blk = blockIdx.x & 15;
  int n0  = (blk << 12) + threadIdx.x;  // 4096 anchors per block
  if (threadIdx.x < NM) {
    float4 t4 = ((const float4*)tb)[b * NM + threadIdx.x];
    tbs4[threadIdx.x] = t4;
    tarea[threadIdx.x] = (t4.z - t4.x) * (t4.w - t4.y);
  }
  if (threadIdx.x < NBINS) lhist[threadIdx.x] = 0u;
  __syncthreads();

  // ---- decode 4 anchors ----
  float dv[APT][4];
  float areaA[APT];
  #pragma unroll
  for (int j = 0; j < APT; ++j) {
    int n = n0 + j * IOU_TPB;
    float4 a4 = ((const float4*)anchors)[n];
    float aw = a4.z - a4.x, ah = a4.w - a4.y;
    float acx = a4.x + 0.5f * aw, acy = a4.y + 0.5f * ah;
    size_t rb = ((size_t)b * 4) * NANCH + n;
    float rx = reg[rb];
    float ry = reg[rb + (size_t)NANCH];
    float rw = reg[rb + 2 * (size_t)NANCH];
    float rh = reg[rb + 3 * (size_t)NANCH];
    float cx = acx + rx * aw, cy = acy + ry * ah;
    float w = aw * expf(rw), h = ah * expf(rh);
    dv[j][0] = cx - 0.5f * w;
    dv[j][1] = cy - 0.5f * h;
    dv[j][2] = cx + 0.5f * w;
    dv[j][3] = cy + 0.5f * h;
    areaA[j] = (dv[j][2] - dv[j][0]) * (dv[j][3] - dv[j][1]);
  }

  // ---- cross-mult argmax over 20 boxes (m outer, anchors inner) ----
  float bI[APT], bU[APT];
  int   bM[APT];
  {
    float4 t = tbs4[0];
    float ab = tarea[0];
    #pragma unroll
    for (int j = 0; j < APT; ++j) {
      float lx = fmaxf(dv[j][0], t.x), ly = fmaxf(dv[j][1], t.y);
      float rx2 = fminf(dv[j][2], t.z), ry2 = fminf(dv[j][3], t.w);
      float iw = fmaxf(rx2 - lx, 0.0f), ih = fmaxf(ry2 - ly, 0.0f);
      float inter = iw * ih;
      bI[j] = inter;
      bU[j] = areaA[j] + ab - inter;
      bM[j] = 0;
    }
  }
  #pragma unroll
  for (int m = 1; m < NM; ++m) {
    float4 t = tbs4[m];
    float ab = tarea[m];
    #pragma unroll
    for (int j = 0; j < APT; ++j) {
      float lx = fmaxf(dv[j][0], t.x), ly = fmaxf(dv[j][1], t.y);
      float rx2 = fminf(dv[j][2], t.z), ry2 = fminf(dv[j][3], t.w);
      float iw = fmaxf(rx2 - lx, 0.0f), ih = fmaxf(ry2 - ly, 0.0f);
      float inter = iw * ih;
      float uni = areaA[j] + ab - inter;
      // inter/uni > bI/bU  <=>  inter*bU > bI*uni  (both unions > 0)
      if (inter * bU[j] > bI[j] * uni) { bI[j] = inter; bU[j] = uni; bM[j] = m; }
    }
  }

  // ---- finalize miou/midx, counts, LDS hist ----
  float tv[APT];
  int   ti[APT];
  int cp = 0, cn = 0;
  #pragma unroll
  for (int j = 0; j < APT; ++j) {
    int n = n0 + j * IOU_TPB;
    size_t idx = (size_t)b * NANCH + n;
    float q = bI[j] / fmaxf(bU[j], 1e-7f);   // IEEE, matches reference
    miou[idx] = q;
    midx[idx] = bM[j];
    tv[j] = q;
    ti[j] = n;
    bool p  = (q >= POS_THR);
    bool ng = (q < NEG_THR);
    cp += __popcll(__ballot(p));
    cn += __popcll(__ballot(ng));
    float sc = scores[idx];
    if (ng) atomicAdd(&lhist[score_bin(sc)], 1u);
  }
  int lane = threadIdx.x & 63;
  if (lane == 0) {
    if (cp) atomicAdd(&pos_cnt[b], cp);
    if (cn) atomicAdd(&neg_cnt[b], cn);
  }

  // ---- flush LDS hist: <=256 global atomics per block (vs 4096 direct) ----
  __syncthreads();
  if (threadIdx.x < NBINS) {
    unsigned c = lhist[threadIdx.x];
    if (c) atomicAdd(&hist[b * NBINS + threadIdx.x], c);
  }

  // ---- barrier-free wave top-10 over the wave's 256 anchors ----
  int wid = threadIdx.x >> 6;
  size_t coff = ((size_t)b * 256 + blk * 16 + wid) * MIN_POS_TOPK;
  for (int it = 0; it < MIN_POS_TOPK; ++it) {
    float mv = tv[0]; int mi_ = ti[0];
    #pragma unroll
    for (int j = 1; j < APT; ++j) {
      if (tv[j] > mv || (tv[j] == mv && ti[j] < mi_)) { mv = tv[j]; mi_ = ti[j]; }
    }
    argmax64(mv, mi_);
    if (lane == 0) { cand_val[coff + it] = mv; cand_idx[coff + it] = mi_; }
    #pragma unroll
    for (int j = 0; j < APT; ++j) {
      if (ti[j] == mi_) tv[j] = -2.0f;
    }
  }
}

// ---------- K2 (fused): blocks 0..15 top-10 merge, blocks 16..31 bucket pick ----------
__global__ __launch_bounds__(256)
void k_mid(const float* __restrict__ cand_val, const int* __restrict__ cand_idx,
           const unsigned* __restrict__ hist,
           const int* __restrict__ pos_cnt, const int* __restrict__ neg_cnt,
           int* __restrict__ num_pos, int* __restrict__ use_fb,
           int* __restrict__ top10,
           int* __restrict__ subsample, int* __restrict__ bucket,
           int* __restrict__ below, int* __restrict__ total_samples) {
  if (blockIdx.x < NB) {
    // ---- top-10 merge over 2560 candidates ----
    int b = blockIdx.x;
    __shared__ float cv[NCAND];
    __shared__ int   ci[NCAND];
    __shared__ float swv[4];
    __shared__ int   swi[4];
    __shared__ int   sel[MIN_POS_TOPK];
    for (int j = threadIdx.x; j < NCAND; j += 256) {
      cv[j] = cand_val[(size_t)b * NCAND + j];
      ci[j] = cand_idx[(size_t)b * NCAND + j];
    }
    __syncthreads();
    int wid = threadIdx.x >> 6;
    for (int it = 0; it < MIN_POS_TOPK; ++it) {
      float v = -2.0f; int i = INT_MAX;
      for (int j = threadIdx.x; j < NCAND; j += 256) {
        if (cv[j] > v || (cv[j] == v && ci[j] < i)) { v = cv[j]; i = ci[j]; }
      }
      argmax64(v, i);
      if ((threadIdx.x & 63) == 0) { swv[wid] = v; swi[wid] = i; }
      __syncthreads();
      float bv = swv[0]; int bi = swi[0];
      #pragma unroll
      for (int w = 1; w < 4; ++w) {
        if (swv[w] > bv || (swv[w] == bv && swi[w] < bi)) { bv = swv[w]; bi = swi[w]; }
      }
      if (threadIdx.x == 0) sel[it] = bi;
      for (int j = threadIdx.x; j < NCAND; j += 256) {
        if (ci[j] == bi) cv[j] = -2.0f;
      }
      __syncthreads();
    }
    if (threadIdx.x < MIN_POS_TOPK) top10[b * MIN_POS_TOPK + threadIdx.x] = sel[threadIdx.x];
    if (threadIdx.x == 0) {
      int pc = pos_cnt[b];
      int fb = (pc < MIN_POS_TOPK) ? 1 : 0;
      use_fb[b] = fb;
      num_pos[b] = fb ? MIN_POS_TOPK : pc;
    }
  } else {
    // ---- bucket pick for negative subsampling (256 bins) ----
    int b = blockIdx.x - NB;
    int pc = pos_cnt[b];
    int np = (pc < MIN_POS_TOPK) ? MIN_POS_TOPK : pc;
    int nc = neg_cnt[b];
    int k = NEG_POS_RATIO * np;
    if (nc <= k) {
      if (threadIdx.x == 0) {
        subsample[b] = 0;
        bucket[b] = -1;
        below[b] = 0;
        total_samples[b] = np + nc;
      }
      return;
    }
    const unsigned* h = hist + (size_t)b * NBINS;
    __shared__ unsigned psum[NBINS];
    if (threadIdx.x < NBINS) psum[threadIdx.x] = h[threadIdx.x];
    __syncthreads();
    if (threadIdx.x == 0) {
      unsigned cum = 0;
      int bkt = NBINS - 1;
      for (int t = 0; t < NBINS; ++t) {
        if (cum + psum[t] >= (unsigned)k) { bkt = t; break; }
        cum += psum[t];
      }
      subsample[b] = 1;
      bucket[b] = bkt;
      below[b] = (int)cum;
      total_samples[b] = np + k;
    }
  }
}

// ---------- K3: gather boundary-bucket elements ----------
__global__ __launch_bounds__(256)
void k_gather(const float* __restrict__ miou, const float* __restrict__ scores,
              const int* __restrict__ subsample, const int* __restrict__ bucket,
              unsigned* __restrict__ eqb, int* __restrict__ eqi,
              int* __restrict__ eqcnt) {
  int b = blockIdx.x >> 8;
  if (!subsample[b]) return;
  int n = ((blockIdx.x & 255) << 8) | threadIdx.x;
  int bkt = bucket[b];
  size_t idx = (size_t)b * NANCH + n;
  if (miou[idx] < NEG_THR) {
    float sc = scores[idx];
    if ((int)score_bin(sc) == bkt) {
      int slot = atomicAdd(&eqcnt[b], 1);
      if (slot < EQCAP) {
        eqb[(size_t)b * EQCAP + slot] = __float_as_uint(sc);
        eqi[(size_t)b * EQCAP + slot] = n;
      }
    }
  }
}

// ---------- K4: rank within bucket -> exact cut (vbits, idx_cut) ----------
__global__ __launch_bounds__(256)
void k_rank(const unsigned* __restrict__ eqb, const int* __restrict__ eqi,
            const int* __restrict__ eqcnt, const int* __restrict__ subsample,
            const int* __restrict__ num_pos, const int* __restrict__ below,
            unsigned* __restrict__ vbits_out, int* __restrict__ idx_cut) {
  int b = blockIdx.x;
  if (!subsample[b]) {
    if (threadIdx.x == 0) { vbits_out[b] = 0u; idx_cut[b] = -1; }
    return;
  }
  int E = eqcnt[b]; if (E > EQCAP) E = EQCAP;
  int r = NEG_POS_RATIO * num_pos[b] - below[b];   // 1-based rank within bucket
  __shared__ unsigned sb_[EQCAP];
  __shared__ int      si_[EQCAP];
  for (int j = threadIdx.x; j < E; j += 256) {
    sb_[j] = eqb[(size_t)b * EQCAP + j];
    si_[j] = eqi[(size_t)b * EQCAP + j];
  }
  __syncthreads();
  for (int e = threadIdx.x; e < E; e += 256) {
    unsigned mb = sb_[e]; int mi = si_[e];
    int rank = 0;
    for (int j = 0; j < E; ++j) {
      unsigned ob = sb_[j]; int oi = si_[j];
      rank += (ob < mb || (ob == mb && oi < mi)) ? 1 : 0;
    }
    if (rank == r - 1) { vbits_out[b] = mb; idx_cut[b] = mi; }
  }
}

// ---------- K5: per-anchor loss accumulation ----------
__global__ __launch_bounds__(256)
void k_loss(const float* __restrict__ cls, const float* __restrict__ reg,
            const float* __restrict__ anchors, const float* __restrict__ tb,
            const int* __restrict__ tl, const float* __restrict__ scores,
            const float* __restrict__ miou, const int* __restrict__ midx,
            const int* __restrict__ use_fb, const int* __restrict__ top10,
            const int* __restrict__ subsample, const unsigned* __restrict__ vbits,
            const int* __restrict__ idx_cut,
            float* __restrict__ sums /* [NB][3] : pos, neg, reg */) {
  int b = blockIdx.x >> 8;
  int n = ((blockIdx.x & 255) << 8) | threadIdx.x;
  __shared__ int s_top10[MIN_POS_TOPK];
  __shared__ int s_usefb, s_sub, s_cut;
  __shared__ unsigned s_vb;
  __shared__ float accp, accn, accr;
  if (threadIdx.x < MIN_POS_TOPK) s_top10[threadIdx.x] = top10[b * MIN_POS_TOPK + threadIdx.x];
  if (threadIdx.x == 0) {
    s_usefb = use_fb[b]; s_sub = subsample[b]; s_cut = idx_cut[b]; s_vb = vbits[b];
    accp = 0.0f; accn = 0.0f; accr = 0.0f;
  }
  __syncthreads();

  size_t idx = (size_t)b * NANCH + n;
  float mi = miou[idx];

  bool pos;
  if (s_usefb) {
    pos = false;
    #pragma unroll
    for (int i = 0; i < MIN_POS_TOPK; ++i) pos |= (s_top10[i] == n);
  } else {
    pos = (mi >= POS_THR);
  }
  bool neg = (mi < NEG_THR);
  bool nsel = false;
  if (neg) {
    if (!s_sub) nsel = true;
    else {
      unsigned sb = __float_as_uint(scores[idx]);
      nsel = (sb < s_vb) || (sb == s_vb && n <= s_cut);
    }
  }

  float cp = 0.0f, cn = 0.0f, rg = 0.0f;
  if (pos || nsel) {
    int mx = 0, t = 0;
    if (pos) { mx = midx[idx]; t = tl[b * NM + mx]; }
    size_t cb = ((size_t)b * NC) * NANCH + n;
    float mxl = -3.0e38f, l0 = 0.0f, lt = 0.0f;
    for (int c = 0; c < NC; ++c) {
      float l = cls[cb + (size_t)c * NANCH];
      if (c == 0) l0 = l;
      if (c == t) lt = l;
      mxl = fmaxf(mxl, l);
    }
    float se = 0.0f;
    for (int c = 0; c < NC; ++c) {
      float l = cls[cb + (size_t)c * NANCH];
      se += expf(l - mxl);
    }
    float lse = mxl + logf(se);
    if (nsel) {
      float ce = lse - l0;
      float pt = expf(-ce);
      float om = 1.0f - pt;
      cn = F_ALPHA * om * om * ce;
    }
    if (pos) {
      float ce = lse - lt;
      float pt = expf(-ce);
      float om = 1.0f - pt;
      cp = F_ALPHA * om * om * ce;
      // decode + GIoU vs matched GT
      const float4 a4 = ((const float4*)anchors)[n];
      float aw = a4.z - a4.x, ah = a4.w - a4.y;
      float acx = a4.x + 0.5f * aw, acy = a4.y + 0.5f * ah;
      size_t rb = ((size_t)b * 4) * NANCH + n;
      float rx = reg[rb];
      float ry = reg[rb + (size_t)NANCH];
      float rw = reg[rb + 2 * (size_t)NANCH];
      float rh = reg[rb + 3 * (size_t)NANCH];
      float ccx = acx + rx * aw, ccy = acy + ry * ah;
      float w = aw * expf(rw), h = ah * expf(rh);
      float d0 = ccx - 0.5f * w, d1 = ccy - 0.5f * h;
      float d2 = ccx + 0.5f * w, d3 = ccy + 0.5f * h;
      const float* g = tb + ((size_t)b * NM + mx) * 4;
      float gx1 = g[0], gy1 = g[1], gx2 = g[2], gy2 = g[3];
      float area_a = (d2 - d0) * (d3 - d1);
      float area_b = (gx2 - gx1) * (gy2 - gy1);
      float lx = fmaxf(d0, gx1), ly = fmaxf(d1, gy1);
      float rx2 = fminf(d2, gx2), ry2 = fminf(d3, gy2);
      float iw = fmaxf(rx2 - lx, 0.0f), ih = fmaxf(ry2 - ly, 0.0f);
      float inter = iw * ih;
      float uni = area_a + area_b - inter;
      float iou = inter / fmaxf(uni, 1e-7f);
      float ex1 = fminf(d0, gx1), ey1 = fminf(d1, gy1);
      float ex2 = fmaxf(d2, gx2), ey2 = fmaxf(d3, gy2);
      float ew = fmaxf(ex2 - ex1, 0.0f), eh = fmaxf(ey2 - ey1, 0.0f);
      float enc = ew * eh;
      float giou = iou - (enc - uni) / fmaxf(enc, 1e-7f);
      rg = 1.0f - giou;
    }
  }

  if (cp != 0.0f) atomicAdd(&accp, cp);
  if (cn != 0.0f) atomicAdd(&accn, cn);
  if (rg != 0.0f) atomicAdd(&accr, rg);
  __syncthreads();
  if (threadIdx.x == 0) {
    if (accp != 0.0f) atomicAdd(&sums[b * 3 + 0], accp);
    if (accn != 0.0f) atomicAdd(&sums[b * 3 + 1], accn);
    if (accr != 0.0f) atomicAdd(&sums[b * 3 + 2], accr);
  }
}

// ---------- K6: finalize ----------
__global__ void k_final(const float* __restrict__ sums,
                        const int* __restrict__ total_samples,
                        const int* __restrict__ num_pos,
                        float* __restrict__ out) {
  if (threadIdx.x == 0 && blockIdx.x == 0) {
    float cm = 0.0f, rm = 0.0f;
    for (int b = 0; b < NB; ++b) {
      int ts = total_samples[b]; if (ts < 1) ts = 1;
      int np = num_pos[b]; if (np < 1) np = 1;
      cm += (sums[b * 3 + 0] + sums[b * 3 + 1]) / (float)ts;
      rm += sums[b * 3 + 2] / (float)np;
    }
    out[0] = cm / (float)NB + rm / (float)NB;
  }
}

extern "C" void kernel_launch(void* const* d_in, const int* in_sizes, int n_in,
                              void* d_out, int out_size, void* d_ws, size_t ws_size,
                              hipStream_t stream) {
  const float* cls     = (const float*)d_in[0];
  const float* reg     = (const float*)d_in[1];
  const float* anchors = (const float*)d_in[2];
  const float* tb      = (const float*)d_in[3];
  const int*   tl      = (const int*)d_in[4];
  const float* scores  = (const float*)d_in[5];
  float* out = (float*)d_out;

  char* ws = (char*)d_ws;
  size_t off = 0;
  float* miou = (float*)(ws + off);            off += (size_t)4 * NB * NANCH;
  int*   midx = (int*)(ws + off);              off += (size_t)4 * NB * NANCH;
  unsigned* hist = (unsigned*)(ws + off);      off += (size_t)4 * NB * NBINS;
  float* cand_val = (float*)(ws + off);        off += (size_t)4 * NB * NCAND;
  int*   cand_idx = (int*)(ws + off);          off += (size_t)4 * NB * NCAND;
  unsigned* eqb = (unsigned*)(ws + off);       off += (size_t)4 * NB * EQCAP;
  int*   eqi = (int*)(ws + off);               off += (size_t)4 * NB * EQCAP;
  int* scal = (int*)(ws + off);
  int* pos_cnt       = scal;
  int* neg_cnt       = scal + NB;
  int* num_pos       = scal + 2 * NB;
  int* use_fb        = scal + 3 * NB;
  int* subsample     = scal + 4 * NB;
  int* idx_cut       = scal + 5 * NB;
  unsigned* vbits    = (unsigned*)(scal + 6 * NB);
  int* total_samples = scal + 7 * NB;
  int* bucket        = scal + 8 * NB;
  int* below         = scal + 9 * NB;
  int* eqcnt         = scal + 10 * NB;
  int* top10         = scal + 11 * NB;                         // NB*10
  float* sums        = (float*)(scal + 11 * NB + MIN_POS_TOPK * NB); // NB*3

  k_init<<<16, 256, 0, stream>>>(hist, pos_cnt, neg_cnt, eqcnt, sums);
  k_iou<<<NB * IOU_BPI, IOU_TPB, 0, stream>>>(reg, anchors, tb, scores, miou, midx,
                                              pos_cnt, neg_cnt, hist, cand_val, cand_idx);
  k_mid<<<2 * NB, 256, 0, stream>>>(cand_val, cand_idx, hist, pos_cnt, neg_cnt,
                                    num_pos, use_fb, top10,
                                    subsample, bucket, below, total_samples);
  k_gather<<<NB * 256, 256, 0, stream>>>(miou, scores, subsample, bucket,
                                         eqb, eqi, eqcnt);
  k_rank<<<NB, 256, 0, stream>>>(eqb, eqi, eqcnt, subsample, num_pos, below,
                                 vbits, idx_cut);
  k_loss<<<NB * 256, 256, 0, stream>>>(cls, reg, anchors, tb, tl, scores,
                                       miou, midx, use_fb, top10, subsample,
                                       vbits, idx_cut, sums);
  k_final<<<1, 1, 0, stream>>>(sums, total_samples, num_pos, out);
}